// Round 9
// baseline (2590.816 us; speedup 1.0000x reference)
//
#include <hip/hip_runtime.h>
#include <hip/hip_cooperative_groups.h>
#include <math.h>

namespace cg = cooperative_groups;

#define NN 1024
#define NM (NN*NN)
#define NB 64
#define NBLK 16
#define NW 1152
#define BIG 4096

#define OFF_FVAR  ((size_t)4096)
#define OFF_NOISE ((size_t)(4096 + 16777216))
#define OFF_M4    ((size_t)(4096 + 2*16777216))

// LDS column pad for k_WtW
#define CPAD(c) ((c) + (((c)>>5)<<2))
#define WSTRIDE 140

struct GPParams {
  float tk[16];
  float E[16];
  float G[16];
  float lam[4];
};

// ---------------- small setup ----------------
__global__ void k_prep(const float* __restrict__ logn, const float* __restrict__ cf,
                       const float* __restrict__ logv, GPParams* __restrict__ P)
{
  if (threadIdx.x != 0 || blockIdx.x != 0) return;
  double tk[4][4], Dn[4], T[4][4], U[4][4];
  for (int a=0;a<4;a++) for (int b=0;b<4;b++){
    double s = 0.0;
    for (int r=0;r<2;r++) s += (double)cf[a*2+r]*(double)cf[b*2+r];
    if (a==b) s += exp((double)logv[a]);
    tk[a][b] = s;
  }
  for (int a=0;a<4;a++) Dn[a] = exp((double)logn[a]);
  for (int a=0;a<4;a++) for (int b=0;b<4;b++)
    T[a][b] = tk[a][b]/sqrt(Dn[a]*Dn[b]);
  for (int a=0;a<4;a++) for (int b=0;b<4;b++) U[a][b] = (a==b)?1.0:0.0;
  for (int sweep=0; sweep<40; sweep++){
    for (int p=0;p<3;p++) for (int q=p+1;q<4;q++){
      double apq = T[p][q];
      if (fabs(apq) < 1e-300) continue;
      double tau = (T[q][q]-T[p][p])/(2.0*apq);
      double t = (tau >= 0.0) ? 1.0/(tau + sqrt(1.0+tau*tau))
                              : 1.0/(tau - sqrt(1.0+tau*tau));
      double c = 1.0/sqrt(1.0+t*t), s = t*c;
      for (int k=0;k<4;k++){ double akp=T[k][p], akq=T[k][q];
        T[k][p]=c*akp - s*akq; T[k][q]=s*akp + c*akq; }
      for (int k=0;k<4;k++){ double apk=T[p][k], aqk=T[q][k];
        T[p][k]=c*apk - s*aqk; T[q][k]=s*apk + c*aqk; }
      for (int k=0;k<4;k++){ double ukp=U[k][p], ukq=U[k][q];
        U[k][p]=c*ukp - s*ukq; U[k][q]=s*ukp + c*ukq; }
    }
  }
  double E[4][4], G[4][4];
  for (int a=0;a<4;a++) for (int i=0;i<4;i++) E[a][i] = U[a][i]/sqrt(Dn[a]);
  for (int a=0;a<4;a++) for (int i=0;i<4;i++){
    double s=0; for (int b=0;b<4;b++) s += tk[a][b]*E[b][i];
    G[a][i]=s;
  }
  for (int a=0;a<4;a++) for (int b=0;b<4;b++){
    P->tk[a*4+b] = (float)tk[a][b];
    P->E [a*4+b] = (float)E[a][b];
    P->G [a*4+b] = (float)G[a][b];
  }
  for (int i=0;i<4;i++){
    double l = T[i][i];
    P->lam[i] = (float)(l > 0.0 ? l : 0.0);
  }
}

// ---------------- RBF kernels ----------------
__global__ void k_rbf(const float* __restrict__ X1, const float* __restrict__ X2,
                      const float* __restrict__ logls, float* __restrict__ out)
{
  __shared__ float x1s[16][8];
  __shared__ float x2s[16][8];
  int tx = threadIdx.x, ty = threadIdx.y;
  int tid = ty*16 + tx;
  if (tid < 128){
    int r = tid>>3, d = tid&7;
    x1s[r][d] = X1[((size_t)blockIdx.y*16 + r)*8 + d];
  } else {
    int t2 = tid-128, r = t2>>3, d = t2&7;
    x2s[r][d] = X2[((size_t)blockIdx.x*16 + r)*8 + d];
  }
  __syncthreads();
  float ls2 = expf(2.0f*logls[0]);
  float d2 = 0.f;
  #pragma unroll
  for (int d=0; d<8; d++){ float df = x1s[ty][d]-x2s[tx][d]; d2 += df*df; }
  int i = blockIdx.y*16+ty, j = blockIdx.x*16+tx;
  out[(size_t)i*NN + j] = expf(-0.5f*d2/ls2);
}

__global__ void k_rbfM(const float* __restrict__ X1, const float* __restrict__ logls,
                       const GPParams* __restrict__ P, float* __restrict__ M)
{
  __shared__ float x1s[16][8];
  __shared__ float x2s[16][8];
  int tx = threadIdx.x, ty = threadIdx.y;
  int tid = ty*16 + tx;
  if (tid < 128){
    int r = tid>>3, d = tid&7;
    x1s[r][d] = X1[((size_t)blockIdx.y*16 + r)*8 + d];
  } else {
    int t2 = tid-128, r = t2>>3, d = t2&7;
    x2s[r][d] = X1[((size_t)blockIdx.x*16 + r)*8 + d];
  }
  __syncthreads();
  float ls2 = expf(2.0f*logls[0]);
  float d2 = 0.f;
  #pragma unroll
  for (int d=0; d<8; d++){ float df = x1s[ty][d]-x2s[tx][d]; d2 += df*df; }
  int i = blockIdx.y*16+ty, j = blockIdx.x*16+tx;
  float v = expf(-0.5f*d2/ls2);
  float diag = (i==j) ? 1.f : 0.f;
  size_t idx = (size_t)i*NN + j;
  #pragma unroll
  for (int z=0;z<4;z++)
    M[(size_t)z*NM + idx] = P->lam[z]*v + diag;
}

__global__ void k_uvec(const float* __restrict__ Y, const GPParams* __restrict__ P,
                       float* __restrict__ u)
{
  int n = blockIdx.x*256 + threadIdx.x;
  float y0 = Y[n*4+0], y1 = Y[n*4+1], y2 = Y[n*4+2], y3 = Y[n*4+3];
  #pragma unroll
  for (int i=0;i<4;i++)
    u[i*NN + n] = P->E[0*4+i]*y0 + P->E[1*4+i]*y1 + P->E[2*4+i]*y2 + P->E[3*4+i]*y3;
}

// ---------------- LDS micro-GEMMs ----------------
__device__ __forceinline__ void gemm64(const float* __restrict__ A, const float* __restrict__ B,
                                       float acc[4][4], int r0, int c0)
{
  for (int p=0;p<64;p++){
    float ar[4], bc[4];
    #pragma unroll
    for (int ii=0;ii<4;ii++) ar[ii]=A[(r0+ii)*65+p];
    #pragma unroll
    for (int jj=0;jj<4;jj++) bc[jj]=B[p*65+c0+jj];
    #pragma unroll
    for (int ii=0;ii<4;ii++)
      #pragma unroll
      for (int jj=0;jj<4;jj++) acc[ii][jj] += ar[ii]*bc[jj];
  }
}
__device__ __forceinline__ void gemm64T(const float* __restrict__ A, const float* __restrict__ B,
                                        float acc[4][4], int r0, int c0)
{
  for (int p=0;p<64;p++){
    float ar[4], bc[4];
    #pragma unroll
    for (int ii=0;ii<4;ii++) ar[ii]=A[(r0+ii)*65+p];
    #pragma unroll
    for (int jj=0;jj<4;jj++) bc[jj]=B[(c0+jj)*65+p];
    #pragma unroll
    for (int ii=0;ii<4;ii++)
      #pragma unroll
      for (int jj=0;jj<4;jj++) acc[ii][jj] += ar[ii]*bc[jj];
  }
}

// ---------------- parallel inversion of lower-triangular 64x64 (stride 65) ----------------
__device__ __forceinline__ void inv_lower64(const float* __restrict__ L,
                                            float* __restrict__ inv,
                                            float* __restrict__ tmp, int tid)
{
  for (int idx=tid; idx<4160; idx+=256) inv[idx]=0.f;
  __syncthreads();
  if (tid < 64){
    int b = tid>>3, c = tid&7, base=b*8;
    for (int r=c;r<8;r++){
      float s = (r==c)?1.f:0.f;
      for (int j=c;j<r;j++) s -= L[(base+r)*65 + base+j]*inv[(base+j)*65 + base+c];
      inv[(base+r)*65 + base+c] = s / L[(base+r)*65 + base+r];
    }
  }
  __syncthreads();
  for (int bs=8; bs<=32; bs<<=1){
    int npair = 32/bs;
    int nout = npair*bs*bs;
    for (int idx=tid; idx<nout; idx+=256){
      int p0 = idx/(bs*bs), rem = idx%(bs*bs);
      int r = rem/bs, c = rem%bs, base = p0*2*bs;
      float s=0.f;
      for (int j=c;j<bs;j++)
        s += L[(base+bs+r)*65 + base+j]*inv[(base+j)*65 + base+c];
      tmp[idx]=s;
    }
    __syncthreads();
    for (int idx=tid; idx<nout; idx+=256){
      int p0 = idx/(bs*bs), rem = idx%(bs*bs);
      int r = rem/bs, c = rem%bs, base = p0*2*bs;
      float s=0.f;
      for (int j=0;j<=r;j++)
        s += inv[(base+bs+r)*65 + base+bs+j]*tmp[p0*bs*bs + j*bs + c];
      inv[(base+bs+r)*65 + base+c] = -s;
    }
    __syncthreads();
  }
}

// ---------------- phase bodies ----------------
__device__ void potf2_body(float* M, float* Linv, float* Gbuf, int k, int z, int tid,
                           float* a, float* lo, float* tmp)
{
  float* Mz = M + (size_t)z*NM;
  int base = k*NB;
  __syncthreads();
  for (int idx=tid; idx<4096; idx+=256){
    int r=idx>>6, c=idx&63;
    a[r*65+c] = Mz[(size_t)(base+r)*NN + base + c];
  }
  int r = tid & 63, q = tid >> 6;
  for (int j=0;j<64;j++){
    __syncthreads();
    float d = a[j*65+j];
    float invd = 1.f/d;
    float rs = rsqrtf(d);
    if (q==0){
      if (r == j) lo[j*65+j] = sqrtf(d);
      else if (r > j) lo[r*65+j] = a[r*65+j]*rs;
      else lo[r*65+j] = 0.f;
    }
    if (r > j){
      float lrj = a[r*65+j]*invd;
      for (int c=j+1+q; c<=r; c+=4)
        a[r*65+c] -= lrj * a[c*65+j];
    }
  }
  __syncthreads();
  inv_lower64(lo, a, tmp, tid);
  float* Lg = Linv + ((size_t)z*NBLK + k)*(NB*NB);
  float* Td = Mz + (size_t)base*NN + base;
  for (int idx=tid; idx<4096; idx+=256){
    int rr=idx>>6, c=idx&63;
    float v = a[rr*65+c];
    Lg[rr*64+c] = v;
    Td[(size_t)rr*NN + c] = v;
  }
  {
    int r0=(tid>>4)*4, c0=(tid&15)*4;
    float g[4][4]={};
    for (int p=0;p<64;p++){
      float ar[4], bc[4];
      #pragma unroll
      for (int ii=0;ii<4;ii++) ar[ii]=a[p*65+r0+ii];
      #pragma unroll
      for (int jj=0;jj<4;jj++) bc[jj]=a[p*65+c0+jj];
      #pragma unroll
      for (int ii=0;ii<4;ii++)
        #pragma unroll
        for (int jj=0;jj<4;jj++) g[ii][jj]+=ar[ii]*bc[jj];
    }
    float* Gg = Gbuf + ((size_t)z*NBLK + k)*4096;
    #pragma unroll
    for (int ii=0;ii<4;ii++)
      *(float4*)&Gg[(r0+ii)*64 + c0] = make_float4(g[ii][0],g[ii][1],g[ii][2],g[ii][3]);
  }
}

__device__ void csf_tile_body(float* M, float* Linv, float* Gbuf, float* Lbuf,
                              int k, int z, int tt, int tid,
                              float* pa, float* pb, float* li)
{
  int i2 = 0;
  while (tt >= i2+1){ tt -= (i2+1); i2++; }
  int bi = k+1+i2, bj = k+1+tt;
  bool fblk = (i2==0);
  float* Mz = M + (size_t)z*NM;
  float* Lb = Lbuf + (size_t)z*NM;
  int ty = tid>>4, tx = tid&15;
  int r0 = ty*4, c0 = tx*4;
  __syncthreads();

  if (fblk){
    const float* Lg = Linv + ((size_t)z*NBLK + k)*(NB*NB);
    for (int idx=tid; idx<4096; idx+=256){
      int r=idx>>6, c=idx&63;
      li[r*65+c] = Lg[idx];
      pa[r*65+c] = Mz[(size_t)(bi*64+r)*NN + k*64 + c];
      pb[r*65+c] = Mz[(size_t)(bi*64+r)*NN + bi*64 + c];
    }
    __syncthreads();
    float sc[4][4]={};
    gemm64T(pa, li, sc, r0, c0);
    #pragma unroll
    for (int ii=0;ii<4;ii++)
      *(float4*)&Lb[(size_t)(bi*64+r0+ii)*NN + k*64+c0] =
        make_float4(sc[ii][0],sc[ii][1],sc[ii][2],sc[ii][3]);
    __syncthreads();
    #pragma unroll
    for (int ii=0;ii<4;ii++)
      #pragma unroll
      for (int jj=0;jj<4;jj++) pa[(r0+ii)*65+c0+jj] = sc[ii][jj];
    __syncthreads();
    float upd[4][4]={};
    gemm64T(pa, pa, upd, r0, c0);
    #pragma unroll
    for (int ii=0;ii<4;ii++)
      #pragma unroll
      for (int jj=0;jj<4;jj++) pb[(r0+ii)*65+c0+jj] -= upd[ii][jj];
    int r = tid & 63, q = tid >> 6;
    for (int j=0;j<64;j++){
      __syncthreads();
      float d = pb[j*65+j];
      float invd = 1.f/d;
      float rs = rsqrtf(d);
      if (q==0){
        if (r == j) li[j*65+j] = sqrtf(d);
        else if (r > j) li[r*65+j] = pb[r*65+j]*rs;
        else li[r*65+j] = 0.f;
      }
      if (r > j){
        float lrj = pb[r*65+j]*invd;
        for (int c=j+1+q; c<=r; c+=4)
          pb[r*65+c] -= lrj * pb[c*65+j];
      }
    }
    __syncthreads();
    inv_lower64(li, pa, pb, tid);
    float* Lg2 = Linv + ((size_t)z*NBLK + (k+1))*(NB*NB);
    float* Td  = Mz + (size_t)(bi*64)*NN + bi*64;
    for (int idx=tid; idx<4096; idx+=256){
      int rr=idx>>6, c=idx&63;
      float v = pa[rr*65+c];
      Lg2[rr*64+c] = v;
      Td[(size_t)rr*NN + c] = v;
    }
    {
      float g[4][4]={};
      for (int p=0;p<64;p++){
        float ar[4], bc[4];
        #pragma unroll
        for (int ii=0;ii<4;ii++) ar[ii]=pa[p*65+r0+ii];
        #pragma unroll
        for (int jj=0;jj<4;jj++) bc[jj]=pa[p*65+c0+jj];
        #pragma unroll
        for (int ii=0;ii<4;ii++)
          #pragma unroll
          for (int jj=0;jj<4;jj++) g[ii][jj]+=ar[ii]*bc[jj];
      }
      float* Gg = Gbuf + ((size_t)z*NBLK + (k+1))*4096;
      #pragma unroll
      for (int ii=0;ii<4;ii++)
        *(float4*)&Gg[(r0+ii)*64 + c0] = make_float4(g[ii][0],g[ii][1],g[ii][2],g[ii][3]);
    }
  } else {
    const float* Gg = Gbuf + ((size_t)z*NBLK + k)*4096;
    for (int idx=tid; idx<4096; idx+=256){
      int r=idx>>6, c=idx&63;
      li[r*65+c] = Gg[idx];
      pa[r*65+c] = Mz[(size_t)(bi*64+r)*NN + k*64 + c];
      pb[r*65+c] = Mz[(size_t)(bj*64+r)*NN + k*64 + c];
    }
    __syncthreads();
    float t[4][4]={};
    gemm64(pa, li, t, r0, c0);
    __syncthreads();
    #pragma unroll
    for (int ii=0;ii<4;ii++)
      #pragma unroll
      for (int jj=0;jj<4;jj++) li[(r0+ii)*65+c0+jj] = t[ii][jj];
    __syncthreads();
    float upd[4][4]={};
    gemm64T(li, pb, upd, r0, c0);
    #pragma unroll
    for (int ii=0;ii<4;ii++){
      float4* ptr = (float4*)&Mz[(size_t)(bi*64+r0+ii)*NN + bj*64+c0];
      float4 v = *ptr;
      v.x-=upd[ii][0]; v.y-=upd[ii][1]; v.z-=upd[ii][2]; v.w-=upd[ii][3];
      *ptr = v;
    }
    if (bj == k+1){
      __syncthreads();
      const float* Lg = Linv + ((size_t)z*NBLK + k)*(NB*NB);
      for (int idx=tid; idx<4096; idx+=256){
        int r=idx>>6, c=idx&63;
        pb[r*65+c] = Lg[idx];
      }
      __syncthreads();
      float sc[4][4]={};
      gemm64T(pa, pb, sc, r0, c0);
      #pragma unroll
      for (int ii=0;ii<4;ii++)
        *(float4*)&Lb[(size_t)(bi*64+r0+ii)*NN + k*64+c0] =
          make_float4(sc[ii][0],sc[ii][1],sc[ii][2],sc[ii][3]);
    }
  }
}

__device__ void dbl1_body(const float* Lbuf, const float* Linv, float* Tinv,
                          int pair, int z, int tid, float* l21, float* ai, float* tt)
{
  int b0 = 2*pair, b1 = 2*pair+1;
  const float* Lb = Lbuf + (size_t)z*NM;
  const float* La = Linv + ((size_t)z*NBLK + b0)*(NB*NB);
  const float* Lc = Linv + ((size_t)z*NBLK + b1)*(NB*NB);
  __syncthreads();
  for (int idx=tid; idx<4096; idx+=256){
    int r=idx>>6, c=idx&63;
    l21[r*65+c] = Lb[(size_t)(b1*64+r)*NN + b0*64 + c];
    ai[r*65+c]  = La[idx];
  }
  __syncthreads();
  int ty=tid>>4, tx=tid&15, r0=ty*4, c0=tx*4;
  float acc[4][4]={};
  gemm64(l21, ai, acc, r0, c0);
  __syncthreads();
  #pragma unroll
  for (int ii=0;ii<4;ii++)
    #pragma unroll
    for (int jj=0;jj<4;jj++) tt[(r0+ii)*65 + c0+jj] = acc[ii][jj];
  for (int idx=tid; idx<4096; idx+=256){
    int r=idx>>6, c=idx&63;
    ai[r*65+c] = Lc[idx];
  }
  __syncthreads();
  float fin[4][4]={};
  gemm64(ai, tt, fin, r0, c0);
  float* Tz = Tinv + (size_t)z*NM;
  #pragma unroll
  for (int ii=0;ii<4;ii++){
    float4 v = make_float4(-fin[ii][0],-fin[ii][1],-fin[ii][2],-fin[ii][3]);
    *(float4*)&Tz[(size_t)(b1*64+r0+ii)*NN + b0*64+c0] = v;
  }
}

__device__ void dblT_body(const float* Lbuf, const float* Tinv, float* tb,
                          int g64, int rr, int z, int tid, float* lt, float* rt)
{
  int tpp = g64*g64;
  int pair = rr / tpp;
  int tt2 = rr % tpp;
  int ti = tt2 / g64, tj = tt2 % g64;
  int b0 = 2*pair*g64, b1 = b0 + g64;
  const float* Lb = Lbuf + (size_t)z*NM;
  const float* Tz = Tinv + (size_t)z*NM;
  int ty=tid>>4, tx=tid&15, r0=ty*4, c0=tx*4;
  float acc[4][4]={};
  __syncthreads();
  for (int kb=tj; kb<g64; kb++){
    for (int idx=tid; idx<4096; idx+=256){
      int r=idx>>6, c=idx&63;
      lt[r*65+c] = Lb[(size_t)((b1+ti)*64+r)*NN + (b0+kb)*64 + c];
      rt[r*65+c] = Tz[(size_t)((b0+kb)*64+r)*NN + (b0+tj)*64 + c];
    }
    __syncthreads();
    gemm64(lt, rt, acc, r0, c0);
    __syncthreads();
  }
  int g = g64*64;
  float* tz = tb + (size_t)z*262144 + (size_t)pair*g*g;
  #pragma unroll
  for (int ii=0;ii<4;ii++){
    float4 v = make_float4(acc[ii][0],acc[ii][1],acc[ii][2],acc[ii][3]);
    *(float4*)&tz[(size_t)(ti*64+r0+ii)*g + tj*64+c0] = v;
  }
}

__device__ void dblC_body(const float* tb, float* Tinv,
                          int g64, int rr, int z, int tid, float* lt, float* rt)
{
  int tpp = g64*g64;
  int pair = rr / tpp;
  int tt2 = rr % tpp;
  int ti = tt2 / g64, tj = tt2 % g64;
  int b0 = 2*pair*g64, b1 = b0 + g64;
  float* Tz = Tinv + (size_t)z*NM;
  int g = g64*64;
  const float* tz = tb + (size_t)z*262144 + (size_t)pair*g*g;
  int ty=tid>>4, tx=tid&15, r0=ty*4, c0=tx*4;
  float acc[4][4]={};
  __syncthreads();
  for (int kb=0; kb<=ti; kb++){
    for (int idx=tid; idx<4096; idx+=256){
      int r=idx>>6, c=idx&63;
      lt[r*65+c] = Tz[(size_t)((b1+ti)*64+r)*NN + (b1+kb)*64 + c];
      rt[r*65+c] = tz[(size_t)(kb*64+r)*g + tj*64 + c];
    }
    __syncthreads();
    gemm64(lt, rt, acc, r0, c0);
    __syncthreads();
  }
  #pragma unroll
  for (int ii=0;ii<4;ii++){
    float4 v = make_float4(-acc[ii][0],-acc[ii][1],-acc[ii][2],-acc[ii][3]);
    *(float4*)&Tz[(size_t)((b1+ti)*64+r0+ii)*NN + b0*64+tj*64+c0] = v;
  }
}

__device__ void wgemm_body(const float* Tinv, const float* R, const float* u, float* W,
                           int ct, int bi, int z, int tid, float* lds)
{
  float* At = lds;           // 64*68
  float* Bs = lds + 4352;    // 64*132
  const float* Tz = Tinv + (size_t)z*NM;
  float* Wz = W + (size_t)z*NN*NW;
  int ty = tid>>4, tx = tid&15;
  float areg[16], breg[32];
  float acc[4][8] = {};
  __syncthreads();
  #pragma unroll
  for (int i=0;i<16;i++){
    int idx=i*256+tid, r=idx>>6, c=idx&63;
    areg[i] = Tz[(size_t)(bi*64+r)*NN + c];
  }
  #pragma unroll
  for (int i=0;i<32;i++){
    int idx=i*256+tid, r=idx>>7, c=idx&127;
    breg[i] = (ct<8) ? R[(size_t)r*NN + ct*128 + c]
                     : ((c<4) ? u[c*NN + r] : 0.f);
  }
  for (int kb=0; kb<=bi; kb++){
    __syncthreads();
    #pragma unroll
    for (int i=0;i<16;i++){
      int idx=i*256+tid, r=idx>>6, c=idx&63;
      At[c*68 + r] = areg[i];
    }
    #pragma unroll
    for (int i=0;i<32;i++){
      int idx=i*256+tid, r=idx>>7, c=idx&127;
      Bs[r*132 + c] = breg[i];
    }
    if (kb < bi){
      int kn = kb+1;
      #pragma unroll
      for (int i=0;i<16;i++){
        int idx=i*256+tid, r=idx>>6, c=idx&63;
        areg[i] = Tz[(size_t)(bi*64+r)*NN + kn*64 + c];
      }
      #pragma unroll
      for (int i=0;i<32;i++){
        int idx=i*256+tid, r=idx>>7, c=idx&127;
        int gr = kn*64 + r;
        breg[i] = (ct<8) ? R[(size_t)gr*NN + ct*128 + c]
                         : ((c<4) ? u[c*NN + gr] : 0.f);
      }
    }
    __syncthreads();
    for (int p=0;p<64;p++){
      float4 a4 = *(const float4*)&At[p*68 + ty*4];
      float4 b0 = *(const float4*)&Bs[p*132 + tx*8];
      float4 b1 = *(const float4*)&Bs[p*132 + tx*8 + 4];
      float ar[4]={a4.x,a4.y,a4.z,a4.w};
      float bc[8]={b0.x,b0.y,b0.z,b0.w,b1.x,b1.y,b1.z,b1.w};
      #pragma unroll
      for (int ii=0;ii<4;ii++)
        #pragma unroll
        for (int jj=0;jj<8;jj++) acc[ii][jj] += ar[ii]*bc[jj];
    }
  }
  #pragma unroll
  for (int ii=0;ii<4;ii++){
    size_t row = (size_t)(bi*64 + ty*4 + ii)*NW + ct*128 + tx*8;
    *(float4*)&Wz[row]   = make_float4(acc[ii][0],acc[ii][1],acc[ii][2],acc[ii][3]);
    *(float4*)&Wz[row+4] = make_float4(acc[ii][4],acc[ii][5],acc[ii][6],acc[ii][7]);
  }
}

// ---------------- cooperative mega-kernel (grid MUST be 256 blocks = 1/CU) ----------------
__global__ __launch_bounds__(256) void k_mega(float* M, float* Linv, float* Gbuf, float* Lbuf,
                                              float* tb, float* R, float* u, float* W)
{
  cg::grid_group gg = cg::this_grid();
  __shared__ float lds[12800];
  float* pa = lds;
  float* pb = lds + 4160;
  float* li = lds + 8320;
  int tid = threadIdx.x;

  if (blockIdx.x < 4)
    potf2_body(M, Linv, Gbuf, 0, blockIdx.x, tid, pa, pb, li);
  gg.sync();

  for (int k=0;k<15;k++){
    int nb = 15-k;
    int tpz = nb*(nb+1)/2;
    int ntile = tpz*4;
    for (int t = blockIdx.x; t < ntile; t += gridDim.x){
      int z = t / tpz;
      int tt = t % tpz;
      csf_tile_body(M, Linv, Gbuf, Lbuf, k, z, tt, tid, pa, pb, li);
    }
    gg.sync();
  }

  if (blockIdx.x < 32){
    int pair = blockIdx.x & 7, z = blockIdx.x >> 3;
    dbl1_body(Lbuf, Linv, M, pair, z, tid, pa, pb, li);
  }
  gg.sync();

  for (int g64=2; g64<=8; g64*=2){
    int np = 8/g64, tpp = g64*g64;
    int per_z = np*tpp;
    int ntile = per_z*4;
    for (int t = blockIdx.x; t < ntile; t += gridDim.x){
      int z = t / per_z, rr = t % per_z;
      dblT_body(Lbuf, M, tb, g64, rr, z, tid, pa, pb);
    }
    gg.sync();
    for (int t = blockIdx.x; t < ntile; t += gridDim.x){
      int z = t / per_z, rr = t % per_z;
      dblC_body(tb, M, g64, rr, z, tid, pa, pb);
    }
    gg.sync();
  }

  for (int t = blockIdx.x; t < 576; t += gridDim.x){
    int z = t / 144, rem = t % 144;
    int bi = rem / 9, ct = rem % 9;
    wgemm_body(M, R, u, W, ct, bi, z, tid, lds);
  }
}

// ---------------- fallback wrappers (round-7 separate-launch chain) ----------------
__global__ __launch_bounds__(256) void kw_potf2(float* M, float* Linv, float* Gbuf, int k)
{
  __shared__ float lds[12800];
  potf2_body(M, Linv, Gbuf, k, blockIdx.x, threadIdx.x, lds, lds+4160, lds+8320);
}
__global__ __launch_bounds__(256) void kw_csf(float* M, float* Linv, float* Gbuf, float* Lbuf, int k)
{
  __shared__ float lds[12800];
  csf_tile_body(M, Linv, Gbuf, Lbuf, k, blockIdx.z, blockIdx.x, threadIdx.x,
                lds, lds+4160, lds+8320);
}
__global__ __launch_bounds__(256) void kw_dbl1(const float* Lbuf, const float* Linv, float* Tinv)
{
  __shared__ float lds[12800];
  dbl1_body(Lbuf, Linv, Tinv, blockIdx.x, blockIdx.y, threadIdx.x, lds, lds+4160, lds+8320);
}
__global__ __launch_bounds__(256) void kw_dblT(const float* Lbuf, const float* Tinv, float* tb, int g64)
{
  __shared__ float lds[8320];
  dblT_body(Lbuf, Tinv, tb, g64, blockIdx.x, blockIdx.y, threadIdx.x, lds, lds+4160);
}
__global__ __launch_bounds__(256) void kw_dblC(const float* tb, float* Tinv, int g64)
{
  __shared__ float lds[8320];
  dblC_body(tb, Tinv, g64, blockIdx.x, blockIdx.y, threadIdx.x, lds, lds+4160);
}
__global__ __launch_bounds__(256) void kw_wgemm(const float* Tinv, const float* R,
                                                const float* u, float* W)
{
  __shared__ float lds[12800];
  wgemm_body(Tinv, R, u, W, blockIdx.x, blockIdx.y, blockIdx.z, threadIdx.x, lds);
}

// ---------------- Q partials = W^T W (K-split 3), triangle tiles + mirror ----------------
__global__ __launch_bounds__(256) void k_WtW(const float* __restrict__ W,
                                             float* __restrict__ Qa, float* __restrict__ Qb,
                                             float* __restrict__ Qc)
{
  int z = blockIdx.z;
  int ks = blockIdx.x / 36;
  int tt = blockIdx.x % 36, mi = 0;
  while (tt >= mi+1){ tt -= (mi+1); mi++; }
  int mj = tt;
  const float* Wz = W + (size_t)z*NN*NW;
  float* Qz = (ks==0 ? Qa : (ks==1 ? Qb : Qc)) + (size_t)z*NM;
  int mi0 = mi*128, mj0 = mj*128;
  __shared__ float as[16*WSTRIDE];
  __shared__ float bs[16*WSTRIDE];
  int tid = threadIdx.x;
  int ty = tid>>4, tx = tid&15;
  float areg[8], breg[8];
  float acc[8][8] = {};
  int nbase = ks*352;
  int nsteps = (ks==2)?20:22;   // 352+352+320 = 1024
  #pragma unroll
  for (int i=0;i<8;i++){
    int idx=i*256+tid, r=idx>>7, c=idx&127;
    areg[i] = Wz[(size_t)(nbase+r)*NW + mi0 + c];
    breg[i] = Wz[(size_t)(nbase+r)*NW + mj0 + c];
  }
  int ca = CPAD(ty*8), cb = CPAD(tx*8);
  for (int s=0;s<nsteps;s++){
    __syncthreads();
    #pragma unroll
    for (int i=0;i<8;i++){
      int idx=i*256+tid, r=idx>>7, c=idx&127;
      as[r*WSTRIDE+CPAD(c)]=areg[i];
      bs[r*WSTRIDE+CPAD(c)]=breg[i];
    }
    if (s<nsteps-1){
      int n0 = nbase + (s+1)*16;
      #pragma unroll
      for (int i=0;i<8;i++){
        int idx=i*256+tid, r=idx>>7, c=idx&127;
        areg[i] = Wz[(size_t)(n0+r)*NW + mi0 + c];
        breg[i] = Wz[(size_t)(n0+r)*NW + mj0 + c];
      }
    }
    __syncthreads();
    #pragma unroll
    for (int p=0;p<16;p++){
      float4 a0 = *(const float4*)&as[p*WSTRIDE + ca];
      float4 a1 = *(const float4*)&as[p*WSTRIDE + ca + 4];
      float4 b0 = *(const float4*)&bs[p*WSTRIDE + cb];
      float4 b1 = *(const float4*)&bs[p*WSTRIDE + cb + 4];
      float arf[8]={a0.x,a0.y,a0.z,a0.w,a1.x,a1.y,a1.z,a1.w};
      float bcf[8]={b0.x,b0.y,b0.z,b0.w,b1.x,b1.y,b1.z,b1.w};
      #pragma unroll
      for (int ii=0;ii<8;ii++)
        #pragma unroll
        for (int jj=0;jj<8;jj++) acc[ii][jj]+=arf[ii]*bcf[jj];
    }
  }
  for (int ii=0;ii<8;ii++){
    size_t row = (size_t)(mi0 + ty*8 + ii)*NN + mj0 + tx*8;
    *(float4*)&Qz[row]   = make_float4(acc[ii][0],acc[ii][1],acc[ii][2],acc[ii][3]);
    *(float4*)&Qz[row+4] = make_float4(acc[ii][4],acc[ii][5],acc[ii][6],acc[ii][7]);
  }
  if (mi != mj){
    for (int jj=0;jj<8;jj++){
      size_t row = (size_t)(mj0 + tx*8 + jj)*NN + mi0 + ty*8;
      *(float4*)&Qz[row]   = make_float4(acc[0][jj],acc[1][jj],acc[2][jj],acc[3][jj]);
      *(float4*)&Qz[row+4] = make_float4(acc[4][jj],acc[5][jj],acc[6][jj],acc[7][jj]);
    }
  }
}

// ---------------- column-dot partials ----------------
__global__ void k_colmul(const float* __restrict__ W, float* __restrict__ wpart)
{
  int mc = blockIdx.x, z = blockIdx.y, ns = blockIdx.z, tid = threadIdx.x;
  __shared__ float ufs[256];
  const float* Wz = W + (size_t)z*NN*NW;
  ufs[tid] = Wz[(size_t)(ns*256+tid)*NW + 1024 + z];
  __syncthreads();
  int m = mc*256 + tid;
  float acc = 0.f;
  for (int n=0;n<256;n++)
    acc += Wz[(size_t)(ns*256+n)*NW + m]*ufs[n];
  wpart[(size_t)(z*4+ns)*1024 + m] = acc;
}

// ---------------- fmean outputs (outputs 0 and 3) ----------------
__global__ void k_fmeanout(const float* __restrict__ wpart, const GPParams* __restrict__ P,
                           float* __restrict__ out)
{
  int m = blockIdx.x*256 + threadIdx.x;
  float w[4];
  #pragma unroll
  for (int i=0;i<4;i++){
    float s=0.f;
    #pragma unroll
    for (int ns=0;ns<4;ns++) s += wpart[(size_t)(i*4+ns)*1024 + m];
    w[i]=s;
  }
  #pragma unroll
  for (int a=0;a<4;a++){
    float fm = 0.f;
    #pragma unroll
    for (int i=0;i<4;i++) fm += P->G[a*4+i]*w[i];
    out[a*NN + m] = fm;
    out[OFF_M4 + (size_t)m*4 + a] = fm;
  }
}

// ---------------- fvar assembly (output 1) ----------------
__global__ void k_fvar(const float* __restrict__ S, const float* __restrict__ Qa,
                       const float* __restrict__ Qb, const float* __restrict__ Qc,
                       const GPParams* __restrict__ P, float* __restrict__ out)
{
  size_t idx = (size_t)blockIdx.x*256 + threadIdx.x;
  int m = (int)(idx>>10), mp = (int)(idx & 1023);
  float s = S[idx];
  float q[4];
  #pragma unroll
  for (int i=0;i<4;i++)
    q[i] = Qa[(size_t)i*NM + idx] + Qb[(size_t)i*NM + idx] + Qc[(size_t)i*NM + idx];
  float* fv = out + OFF_FVAR;
  #pragma unroll
  for (int a=0;a<4;a++)
    #pragma unroll
    for (int b=0;b<4;b++){
      float val = P->tk[a*4+b]*s;
      #pragma unroll
      for (int i=0;i<4;i++) val -= P->G[a*4+i]*P->G[b*4+i]*q[i];
      fv[(size_t)(a*NN+m)*BIG + (size_t)b*NN + mp] = val;
    }
}

// ---------------- noise output (output 2) — runs last ----------------
__global__ void k_noise(const float* __restrict__ logn, float* __restrict__ out)
{
  size_t idx = (size_t)blockIdx.x*256 + threadIdx.x;
  int row = (int)(idx>>12), col = (int)(idx & 4095);
  out[OFF_NOISE + idx] = (row==col) ? expf(logn[row>>10]) : 0.f;
}

extern "C" void kernel_launch(void* const* d_in, const int* in_sizes, int n_in,
                              void* d_out, int out_size, void* d_ws, size_t ws_size,
                              hipStream_t stream)
{
  const float* X    = (const float*)d_in[0];
  const float* tX   = (const float*)d_in[1];
  const float* Y    = (const float*)d_in[2];
  const float* logn = (const float*)d_in[3];
  const float* cf   = (const float*)d_in[4];
  const float* logv = (const float*)d_in[5];
  const float* logls= (const float*)d_in[6];
  float* out = (float*)d_out;

  // scratch (floats): P(64) u(4096) wpart(16384) R(NM) S(NM) M(4NM)[->Tinv->Qa]
  //                   Linv(262144) Gbuf(262144) TQ(4NM)[tb -> Qc] Lbuf(4NM)[->Qb]
  // W lives in out+OFF_FVAR (overwritten by k_fvar at the end).
  size_t need_floats = 64 + 4096 + 16384
                     + 2*(size_t)NM + 4*(size_t)NM + 262144 + 262144
                     + 4*(size_t)NM + 4*(size_t)NM;
  float* base;
  if (ws_size >= (need_floats + 1024)*sizeof(float)) base = (float*)d_ws;
  else base = out + OFF_NOISE;  // noise region as scratch; k_noise runs last

  GPParams* P  = (GPParams*)base;
  float* u     = base + 64;
  float* wpart = u + 4096;
  float* R     = wpart + 16384;
  float* S     = R + NM;
  float* M     = S + NM;
  float* Linv  = M + 4*(size_t)NM;
  float* Gbuf  = Linv + 262144;
  float* TQ    = Gbuf + 262144;
  float* Lbuf  = TQ + 4*(size_t)NM;
  float* W     = out + OFF_FVAR;
  float* Qa    = M;
  float* Qb    = Lbuf;
  float* Qc    = TQ;
  float* tb    = TQ;

  dim3 b16(16,16);

  k_prep<<<1, 1, 0, stream>>>(logn, cf, logv, P);
  k_rbf <<<dim3(64,64), b16, 0, stream>>>(X,  tX, logls, R);
  k_rbf <<<dim3(64,64), b16, 0, stream>>>(tX, tX, logls, S);
  k_rbfM<<<dim3(64,64), b16, 0, stream>>>(X, logls, P, M);
  k_uvec<<<dim3(4), 256, 0, stream>>>(Y, P, u);

  // one cooperative launch (256 blocks = 1/CU, always co-resident); fallback chain on error
  hipError_t ce;
  {
    void* kargs[] = { (void*)&M, (void*)&Linv, (void*)&Gbuf, (void*)&Lbuf,
                      (void*)&tb, (void*)&R, (void*)&u, (void*)&W };
    ce = hipLaunchCooperativeKernel((const void*)k_mega, dim3(256), dim3(256),
                                    kargs, 0, stream);
  }
  if (ce != hipSuccess){
    (void)hipGetLastError();   // clear sticky error
    kw_potf2<<<dim3(4), 256, 0, stream>>>(M, Linv, Gbuf, 0);
    for (int k=0;k<15;k++){
      int nb = 15-k;
      kw_csf<<<dim3(nb*(nb+1)/2, 1, 4), 256, 0, stream>>>(M, Linv, Gbuf, Lbuf, k);
    }
    kw_dbl1<<<dim3(8,4), 256, 0, stream>>>(Lbuf, Linv, M);
    for (int g64=2; g64<=8; g64*=2){
      int np = 8/g64;
      kw_dblT<<<dim3(np*g64*g64, 4), 256, 0, stream>>>(Lbuf, M, tb, g64);
      kw_dblC<<<dim3(np*g64*g64, 4), 256, 0, stream>>>(tb, M, g64);
    }
    kw_wgemm<<<dim3(9,16,4), 256, 0, stream>>>(M, R, u, W);
  }

  // Q = W^T W (three K-chunk partials)
  k_WtW<<<dim3(108,1,4), 256, 0, stream>>>(W, Qa, Qb, Qc);

  k_colmul<<<dim3(4,4,4), 256, 0, stream>>>(W, wpart);
  k_fmeanout<<<dim3(4), 256, 0, stream>>>(wpart, P, out);
  k_fvar<<<dim3(NM/256), 256, 0, stream>>>(S, Qa, Qb, Qc, P, out);
  k_noise<<<dim3(16777216/256), 256, 0, stream>>>(logn, out); // last: may overwrite scratch
}

// Round 10
// 1870.601 us; speedup vs baseline: 1.3850x; 1.3850x over previous
//
#include <hip/hip_runtime.h>
#include <hip/hip_cooperative_groups.h>
#include <math.h>

namespace cg = cooperative_groups;

#define NN 1024
#define NM (NN*NN)
#define NB 64
#define NBLK 16
#define NW 1152
#define BIG 4096

#define OFF_FVAR  ((size_t)4096)
#define OFF_NOISE ((size_t)(4096 + 16777216))
#define OFF_M4    ((size_t)(4096 + 2*16777216))

// LDS column pad for k_WtW
#define CPAD(c) ((c) + (((c)>>5)<<2))
#define WSTRIDE 140

struct GPParams {
  float tk[16];
  float E[16];
  float G[16];
  float lam[4];
};

// ---------------- small setup ----------------
__global__ void k_prep(const float* __restrict__ logn, const float* __restrict__ cf,
                       const float* __restrict__ logv, GPParams* __restrict__ P)
{
  if (threadIdx.x != 0 || blockIdx.x != 0) return;
  double tk[4][4], Dn[4], T[4][4], U[4][4];
  for (int a=0;a<4;a++) for (int b=0;b<4;b++){
    double s = 0.0;
    for (int r=0;r<2;r++) s += (double)cf[a*2+r]*(double)cf[b*2+r];
    if (a==b) s += exp((double)logv[a]);
    tk[a][b] = s;
  }
  for (int a=0;a<4;a++) Dn[a] = exp((double)logn[a]);
  for (int a=0;a<4;a++) for (int b=0;b<4;b++)
    T[a][b] = tk[a][b]/sqrt(Dn[a]*Dn[b]);
  for (int a=0;a<4;a++) for (int b=0;b<4;b++) U[a][b] = (a==b)?1.0:0.0;
  for (int sweep=0; sweep<40; sweep++){
    for (int p=0;p<3;p++) for (int q=p+1;q<4;q++){
      double apq = T[p][q];
      if (fabs(apq) < 1e-300) continue;
      double tau = (T[q][q]-T[p][p])/(2.0*apq);
      double t = (tau >= 0.0) ? 1.0/(tau + sqrt(1.0+tau*tau))
                              : 1.0/(tau - sqrt(1.0+tau*tau));
      double c = 1.0/sqrt(1.0+t*t), s = t*c;
      for (int k=0;k<4;k++){ double akp=T[k][p], akq=T[k][q];
        T[k][p]=c*akp - s*akq; T[k][q]=s*akp + c*akq; }
      for (int k=0;k<4;k++){ double apk=T[p][k], aqk=T[q][k];
        T[p][k]=c*apk - s*aqk; T[q][k]=s*apk + c*aqk; }
      for (int k=0;k<4;k++){ double ukp=U[k][p], ukq=U[k][q];
        U[k][p]=c*ukp - s*ukq; U[k][q]=s*ukp + c*ukq; }
    }
  }
  double E[4][4], G[4][4];
  for (int a=0;a<4;a++) for (int i=0;i<4;i++) E[a][i] = U[a][i]/sqrt(Dn[a]);
  for (int a=0;a<4;a++) for (int i=0;i<4;i++){
    double s=0; for (int b=0;b<4;b++) s += tk[a][b]*E[b][i];
    G[a][i]=s;
  }
  for (int a=0;a<4;a++) for (int b=0;b<4;b++){
    P->tk[a*4+b] = (float)tk[a][b];
    P->E [a*4+b] = (float)E[a][b];
    P->G [a*4+b] = (float)G[a][b];
  }
  for (int i=0;i<4;i++){
    double l = T[i][i];
    P->lam[i] = (float)(l > 0.0 ? l : 0.0);
  }
}

// ---------------- RBF kernels ----------------
__global__ void k_rbf(const float* __restrict__ X1, const float* __restrict__ X2,
                      const float* __restrict__ logls, float* __restrict__ out)
{
  __shared__ float x1s[16][8];
  __shared__ float x2s[16][8];
  int tx = threadIdx.x, ty = threadIdx.y;
  int tid = ty*16 + tx;
  if (tid < 128){
    int r = tid>>3, d = tid&7;
    x1s[r][d] = X1[((size_t)blockIdx.y*16 + r)*8 + d];
  } else {
    int t2 = tid-128, r = t2>>3, d = t2&7;
    x2s[r][d] = X2[((size_t)blockIdx.x*16 + r)*8 + d];
  }
  __syncthreads();
  float ls2 = expf(2.0f*logls[0]);
  float d2 = 0.f;
  #pragma unroll
  for (int d=0; d<8; d++){ float df = x1s[ty][d]-x2s[tx][d]; d2 += df*df; }
  int i = blockIdx.y*16+ty, j = blockIdx.x*16+tx;
  out[(size_t)i*NN + j] = expf(-0.5f*d2/ls2);
}

__global__ void k_rbfM(const float* __restrict__ X1, const float* __restrict__ logls,
                       const GPParams* __restrict__ P, float* __restrict__ M)
{
  __shared__ float x1s[16][8];
  __shared__ float x2s[16][8];
  int tx = threadIdx.x, ty = threadIdx.y;
  int tid = ty*16 + tx;
  if (tid < 128){
    int r = tid>>3, d = tid&7;
    x1s[r][d] = X1[((size_t)blockIdx.y*16 + r)*8 + d];
  } else {
    int t2 = tid-128, r = t2>>3, d = t2&7;
    x2s[r][d] = X1[((size_t)blockIdx.x*16 + r)*8 + d];
  }
  __syncthreads();
  float ls2 = expf(2.0f*logls[0]);
  float d2 = 0.f;
  #pragma unroll
  for (int d=0; d<8; d++){ float df = x1s[ty][d]-x2s[tx][d]; d2 += df*df; }
  int i = blockIdx.y*16+ty, j = blockIdx.x*16+tx;
  float v = expf(-0.5f*d2/ls2);
  float diag = (i==j) ? 1.f : 0.f;
  size_t idx = (size_t)i*NN + j;
  #pragma unroll
  for (int z=0;z<4;z++)
    M[(size_t)z*NM + idx] = P->lam[z]*v + diag;
}

__global__ void k_uvec(const float* __restrict__ Y, const GPParams* __restrict__ P,
                       float* __restrict__ u)
{
  int n = blockIdx.x*256 + threadIdx.x;
  float y0 = Y[n*4+0], y1 = Y[n*4+1], y2 = Y[n*4+2], y3 = Y[n*4+3];
  #pragma unroll
  for (int i=0;i<4;i++)
    u[i*NN + n] = P->E[0*4+i]*y0 + P->E[1*4+i]*y1 + P->E[2*4+i]*y2 + P->E[3*4+i]*y3;
}

// ---------------- LDS micro-GEMMs ----------------
__device__ __forceinline__ void gemm64(const float* __restrict__ A, const float* __restrict__ B,
                                       float acc[4][4], int r0, int c0)
{
  for (int p=0;p<64;p++){
    float ar[4], bc[4];
    #pragma unroll
    for (int ii=0;ii<4;ii++) ar[ii]=A[(r0+ii)*65+p];
    #pragma unroll
    for (int jj=0;jj<4;jj++) bc[jj]=B[p*65+c0+jj];
    #pragma unroll
    for (int ii=0;ii<4;ii++)
      #pragma unroll
      for (int jj=0;jj<4;jj++) acc[ii][jj] += ar[ii]*bc[jj];
  }
}
__device__ __forceinline__ void gemm64T(const float* __restrict__ A, const float* __restrict__ B,
                                        float acc[4][4], int r0, int c0)
{
  for (int p=0;p<64;p++){
    float ar[4], bc[4];
    #pragma unroll
    for (int ii=0;ii<4;ii++) ar[ii]=A[(r0+ii)*65+p];
    #pragma unroll
    for (int jj=0;jj<4;jj++) bc[jj]=B[(c0+jj)*65+p];
    #pragma unroll
    for (int ii=0;ii<4;ii++)
      #pragma unroll
      for (int jj=0;jj<4;jj++) acc[ii][jj] += ar[ii]*bc[jj];
  }
}

// ---------------- parallel inversion of lower-triangular 64x64 (stride 65) ----------------
__device__ __forceinline__ void inv_lower64(const float* __restrict__ L,
                                            float* __restrict__ inv,
                                            float* __restrict__ tmp, int tid)
{
  for (int idx=tid; idx<4160; idx+=256) inv[idx]=0.f;
  __syncthreads();
  if (tid < 64){
    int b = tid>>3, c = tid&7, base=b*8;
    for (int r=c;r<8;r++){
      float s = (r==c)?1.f:0.f;
      for (int j=c;j<r;j++) s -= L[(base+r)*65 + base+j]*inv[(base+j)*65 + base+c];
      inv[(base+r)*65 + base+c] = s / L[(base+r)*65 + base+r];
    }
  }
  __syncthreads();
  for (int bs=8; bs<=32; bs<<=1){
    int npair = 32/bs;
    int nout = npair*bs*bs;
    for (int idx=tid; idx<nout; idx+=256){
      int p0 = idx/(bs*bs), rem = idx%(bs*bs);
      int r = rem/bs, c = rem%bs, base = p0*2*bs;
      float s=0.f;
      for (int j=c;j<bs;j++)
        s += L[(base+bs+r)*65 + base+j]*inv[(base+j)*65 + base+c];
      tmp[idx]=s;
    }
    __syncthreads();
    for (int idx=tid; idx<nout; idx+=256){
      int p0 = idx/(bs*bs), rem = idx%(bs*bs);
      int r = rem/bs, c = rem%bs, base = p0*2*bs;
      float s=0.f;
      for (int j=0;j<=r;j++)
        s += inv[(base+bs+r)*65 + base+bs+j]*tmp[p0*bs*bs + j*bs + c];
      inv[(base+bs+r)*65 + base+c] = -s;
    }
    __syncthreads();
  }
}

// ---------------- phase bodies ----------------
__device__ void potf2_body(float* M, float* Linv, float* Gbuf, int k, int z, int tid,
                           float* a, float* lo, float* tmp)
{
  float* Mz = M + (size_t)z*NM;
  int base = k*NB;
  __syncthreads();
  for (int idx=tid; idx<4096; idx+=256){
    int r=idx>>6, c=idx&63;
    a[r*65+c] = Mz[(size_t)(base+r)*NN + base + c];
  }
  int r = tid & 63, q = tid >> 6;
  for (int j=0;j<64;j++){
    __syncthreads();
    float d = a[j*65+j];
    float invd = 1.f/d;
    float rs = rsqrtf(d);
    if (q==0){
      if (r == j) lo[j*65+j] = sqrtf(d);
      else if (r > j) lo[r*65+j] = a[r*65+j]*rs;
      else lo[r*65+j] = 0.f;
    }
    if (r > j){
      float lrj = a[r*65+j]*invd;
      for (int c=j+1+q; c<=r; c+=4)
        a[r*65+c] -= lrj * a[c*65+j];
    }
  }
  __syncthreads();
  inv_lower64(lo, a, tmp, tid);
  float* Lg = Linv + ((size_t)z*NBLK + k)*(NB*NB);
  float* Td = Mz + (size_t)base*NN + base;
  for (int idx=tid; idx<4096; idx+=256){
    int rr=idx>>6, c=idx&63;
    float v = a[rr*65+c];
    Lg[rr*64+c] = v;
    Td[(size_t)rr*NN + c] = v;
  }
  {
    int r0=(tid>>4)*4, c0=(tid&15)*4;
    float g[4][4]={};
    for (int p=0;p<64;p++){
      float ar[4], bc[4];
      #pragma unroll
      for (int ii=0;ii<4;ii++) ar[ii]=a[p*65+r0+ii];
      #pragma unroll
      for (int jj=0;jj<4;jj++) bc[jj]=a[p*65+c0+jj];
      #pragma unroll
      for (int ii=0;ii<4;ii++)
        #pragma unroll
        for (int jj=0;jj<4;jj++) g[ii][jj]+=ar[ii]*bc[jj];
    }
    float* Gg = Gbuf + ((size_t)z*NBLK + k)*4096;
    #pragma unroll
    for (int ii=0;ii<4;ii++)
      *(float4*)&Gg[(r0+ii)*64 + c0] = make_float4(g[ii][0],g[ii][1],g[ii][2],g[ii][3]);
  }
}

__device__ void csf_tile_body(float* M, float* Linv, float* Gbuf, float* Lbuf,
                              int k, int z, int tt, int tid,
                              float* pa, float* pb, float* li)
{
  int i2 = 0;
  while (tt >= i2+1){ tt -= (i2+1); i2++; }
  int bi = k+1+i2, bj = k+1+tt;
  bool fblk = (i2==0);
  float* Mz = M + (size_t)z*NM;
  float* Lb = Lbuf + (size_t)z*NM;
  int ty = tid>>4, tx = tid&15;
  int r0 = ty*4, c0 = tx*4;
  __syncthreads();

  if (fblk){
    const float* Lg = Linv + ((size_t)z*NBLK + k)*(NB*NB);
    for (int idx=tid; idx<4096; idx+=256){
      int r=idx>>6, c=idx&63;
      li[r*65+c] = Lg[idx];
      pa[r*65+c] = Mz[(size_t)(bi*64+r)*NN + k*64 + c];
      pb[r*65+c] = Mz[(size_t)(bi*64+r)*NN + bi*64 + c];
    }
    __syncthreads();
    float sc[4][4]={};
    gemm64T(pa, li, sc, r0, c0);
    #pragma unroll
    for (int ii=0;ii<4;ii++)
      *(float4*)&Lb[(size_t)(bi*64+r0+ii)*NN + k*64+c0] =
        make_float4(sc[ii][0],sc[ii][1],sc[ii][2],sc[ii][3]);
    __syncthreads();
    #pragma unroll
    for (int ii=0;ii<4;ii++)
      #pragma unroll
      for (int jj=0;jj<4;jj++) pa[(r0+ii)*65+c0+jj] = sc[ii][jj];
    __syncthreads();
    float upd[4][4]={};
    gemm64T(pa, pa, upd, r0, c0);
    #pragma unroll
    for (int ii=0;ii<4;ii++)
      #pragma unroll
      for (int jj=0;jj<4;jj++) pb[(r0+ii)*65+c0+jj] -= upd[ii][jj];
    int r = tid & 63, q = tid >> 6;
    for (int j=0;j<64;j++){
      __syncthreads();
      float d = pb[j*65+j];
      float invd = 1.f/d;
      float rs = rsqrtf(d);
      if (q==0){
        if (r == j) li[j*65+j] = sqrtf(d);
        else if (r > j) li[r*65+j] = pb[r*65+j]*rs;
        else li[r*65+j] = 0.f;
      }
      if (r > j){
        float lrj = pb[r*65+j]*invd;
        for (int c=j+1+q; c<=r; c+=4)
          pb[r*65+c] -= lrj * pb[c*65+j];
      }
    }
    __syncthreads();
    inv_lower64(li, pa, pb, tid);
    float* Lg2 = Linv + ((size_t)z*NBLK + (k+1))*(NB*NB);
    float* Td  = Mz + (size_t)(bi*64)*NN + bi*64;
    for (int idx=tid; idx<4096; idx+=256){
      int rr=idx>>6, c=idx&63;
      float v = pa[rr*65+c];
      Lg2[rr*64+c] = v;
      Td[(size_t)rr*NN + c] = v;
    }
    {
      float g[4][4]={};
      for (int p=0;p<64;p++){
        float ar[4], bc[4];
        #pragma unroll
        for (int ii=0;ii<4;ii++) ar[ii]=pa[p*65+r0+ii];
        #pragma unroll
        for (int jj=0;jj<4;jj++) bc[jj]=pa[p*65+c0+jj];
        #pragma unroll
        for (int ii=0;ii<4;ii++)
          #pragma unroll
          for (int jj=0;jj<4;jj++) g[ii][jj]+=ar[ii]*bc[jj];
      }
      float* Gg = Gbuf + ((size_t)z*NBLK + (k+1))*4096;
      #pragma unroll
      for (int ii=0;ii<4;ii++)
        *(float4*)&Gg[(r0+ii)*64 + c0] = make_float4(g[ii][0],g[ii][1],g[ii][2],g[ii][3]);
    }
  } else {
    const float* Gg = Gbuf + ((size_t)z*NBLK + k)*4096;
    for (int idx=tid; idx<4096; idx+=256){
      int r=idx>>6, c=idx&63;
      li[r*65+c] = Gg[idx];
      pa[r*65+c] = Mz[(size_t)(bi*64+r)*NN + k*64 + c];
      pb[r*65+c] = Mz[(size_t)(bj*64+r)*NN + k*64 + c];
    }
    __syncthreads();
    float t[4][4]={};
    gemm64(pa, li, t, r0, c0);
    __syncthreads();
    #pragma unroll
    for (int ii=0;ii<4;ii++)
      #pragma unroll
      for (int jj=0;jj<4;jj++) li[(r0+ii)*65+c0+jj] = t[ii][jj];
    __syncthreads();
    float upd[4][4]={};
    gemm64T(li, pb, upd, r0, c0);
    #pragma unroll
    for (int ii=0;ii<4;ii++){
      float4* ptr = (float4*)&Mz[(size_t)(bi*64+r0+ii)*NN + bj*64+c0];
      float4 v = *ptr;
      v.x-=upd[ii][0]; v.y-=upd[ii][1]; v.z-=upd[ii][2]; v.w-=upd[ii][3];
      *ptr = v;
    }
    if (bj == k+1){
      __syncthreads();
      const float* Lg = Linv + ((size_t)z*NBLK + k)*(NB*NB);
      for (int idx=tid; idx<4096; idx+=256){
        int r=idx>>6, c=idx&63;
        pb[r*65+c] = Lg[idx];
      }
      __syncthreads();
      float sc[4][4]={};
      gemm64T(pa, pb, sc, r0, c0);
      #pragma unroll
      for (int ii=0;ii<4;ii++)
        *(float4*)&Lb[(size_t)(bi*64+r0+ii)*NN + k*64+c0] =
          make_float4(sc[ii][0],sc[ii][1],sc[ii][2],sc[ii][3]);
    }
  }
}

__device__ void dbl1_body(const float* Lbuf, const float* Linv, float* Tinv,
                          int pair, int z, int tid, float* l21, float* ai, float* tt)
{
  int b0 = 2*pair, b1 = 2*pair+1;
  const float* Lb = Lbuf + (size_t)z*NM;
  const float* La = Linv + ((size_t)z*NBLK + b0)*(NB*NB);
  const float* Lc = Linv + ((size_t)z*NBLK + b1)*(NB*NB);
  __syncthreads();
  for (int idx=tid; idx<4096; idx+=256){
    int r=idx>>6, c=idx&63;
    l21[r*65+c] = Lb[(size_t)(b1*64+r)*NN + b0*64 + c];
    ai[r*65+c]  = La[idx];
  }
  __syncthreads();
  int ty=tid>>4, tx=tid&15, r0=ty*4, c0=tx*4;
  float acc[4][4]={};
  gemm64(l21, ai, acc, r0, c0);
  __syncthreads();
  #pragma unroll
  for (int ii=0;ii<4;ii++)
    #pragma unroll
    for (int jj=0;jj<4;jj++) tt[(r0+ii)*65 + c0+jj] = acc[ii][jj];
  for (int idx=tid; idx<4096; idx+=256){
    int r=idx>>6, c=idx&63;
    ai[r*65+c] = Lc[idx];
  }
  __syncthreads();
  float fin[4][4]={};
  gemm64(ai, tt, fin, r0, c0);
  float* Tz = Tinv + (size_t)z*NM;
  #pragma unroll
  for (int ii=0;ii<4;ii++){
    float4 v = make_float4(-fin[ii][0],-fin[ii][1],-fin[ii][2],-fin[ii][3]);
    *(float4*)&Tz[(size_t)(b1*64+r0+ii)*NN + b0*64+c0] = v;
  }
}

__device__ void dblT_body(const float* Lbuf, const float* Tinv, float* tb,
                          int g64, int rr, int z, int tid, float* lt, float* rt)
{
  int tpp = g64*g64;
  int pair = rr / tpp;
  int tt2 = rr % tpp;
  int ti = tt2 / g64, tj = tt2 % g64;
  int b0 = 2*pair*g64, b1 = b0 + g64;
  const float* Lb = Lbuf + (size_t)z*NM;
  const float* Tz = Tinv + (size_t)z*NM;
  int ty=tid>>4, tx=tid&15, r0=ty*4, c0=tx*4;
  float acc[4][4]={};
  __syncthreads();
  for (int kb=tj; kb<g64; kb++){
    for (int idx=tid; idx<4096; idx+=256){
      int r=idx>>6, c=idx&63;
      lt[r*65+c] = Lb[(size_t)((b1+ti)*64+r)*NN + (b0+kb)*64 + c];
      rt[r*65+c] = Tz[(size_t)((b0+kb)*64+r)*NN + (b0+tj)*64 + c];
    }
    __syncthreads();
    gemm64(lt, rt, acc, r0, c0);
    __syncthreads();
  }
  int g = g64*64;
  float* tz = tb + (size_t)z*262144 + (size_t)pair*g*g;
  #pragma unroll
  for (int ii=0;ii<4;ii++){
    float4 v = make_float4(acc[ii][0],acc[ii][1],acc[ii][2],acc[ii][3]);
    *(float4*)&tz[(size_t)(ti*64+r0+ii)*g + tj*64+c0] = v;
  }
}

__device__ void dblC_body(const float* tb, float* Tinv,
                          int g64, int rr, int z, int tid, float* lt, float* rt)
{
  int tpp = g64*g64;
  int pair = rr / tpp;
  int tt2 = rr % tpp;
  int ti = tt2 / g64, tj = tt2 % g64;
  int b0 = 2*pair*g64, b1 = b0 + g64;
  float* Tz = Tinv + (size_t)z*NM;
  int g = g64*64;
  const float* tz = tb + (size_t)z*262144 + (size_t)pair*g*g;
  int ty=tid>>4, tx=tid&15, r0=ty*4, c0=tx*4;
  float acc[4][4]={};
  __syncthreads();
  for (int kb=0; kb<=ti; kb++){
    for (int idx=tid; idx<4096; idx+=256){
      int r=idx>>6, c=idx&63;
      lt[r*65+c] = Tz[(size_t)((b1+ti)*64+r)*NN + (b1+kb)*64 + c];
      rt[r*65+c] = tz[(size_t)(kb*64+r)*g + tj*64 + c];
    }
    __syncthreads();
    gemm64(lt, rt, acc, r0, c0);
    __syncthreads();
  }
  #pragma unroll
  for (int ii=0;ii<4;ii++){
    float4 v = make_float4(-acc[ii][0],-acc[ii][1],-acc[ii][2],-acc[ii][3]);
    *(float4*)&Tz[(size_t)((b1+ti)*64+r0+ii)*NN + b0*64+tj*64+c0] = v;
  }
}

__device__ void wgemm_body(const float* Tinv, const float* R, const float* u, float* W,
                           int ct, int bi, int z, int tid, float* lds)
{
  float* At = lds;           // 64*68
  float* Bs = lds + 4352;    // 64*132
  const float* Tz = Tinv + (size_t)z*NM;
  float* Wz = W + (size_t)z*NN*NW;
  int ty = tid>>4, tx = tid&15;
  float areg[16], breg[32];
  float acc[4][8] = {};
  __syncthreads();
  #pragma unroll
  for (int i=0;i<16;i++){
    int idx=i*256+tid, r=idx>>6, c=idx&63;
    areg[i] = Tz[(size_t)(bi*64+r)*NN + c];
  }
  #pragma unroll
  for (int i=0;i<32;i++){
    int idx=i*256+tid, r=idx>>7, c=idx&127;
    breg[i] = (ct<8) ? R[(size_t)r*NN + ct*128 + c]
                     : ((c<4) ? u[c*NN + r] : 0.f);
  }
  for (int kb=0; kb<=bi; kb++){
    __syncthreads();
    #pragma unroll
    for (int i=0;i<16;i++){
      int idx=i*256+tid, r=idx>>6, c=idx&63;
      At[c*68 + r] = areg[i];
    }
    #pragma unroll
    for (int i=0;i<32;i++){
      int idx=i*256+tid, r=idx>>7, c=idx&127;
      Bs[r*132 + c] = breg[i];
    }
    if (kb < bi){
      int kn = kb+1;
      #pragma unroll
      for (int i=0;i<16;i++){
        int idx=i*256+tid, r=idx>>6, c=idx&63;
        areg[i] = Tz[(size_t)(bi*64+r)*NN + kn*64 + c];
      }
      #pragma unroll
      for (int i=0;i<32;i++){
        int idx=i*256+tid, r=idx>>7, c=idx&127;
        int gr = kn*64 + r;
        breg[i] = (ct<8) ? R[(size_t)gr*NN + ct*128 + c]
                         : ((c<4) ? u[c*NN + gr] : 0.f);
      }
    }
    __syncthreads();
    for (int p=0;p<64;p++){
      float4 a4 = *(const float4*)&At[p*68 + ty*4];
      float4 b0 = *(const float4*)&Bs[p*132 + tx*8];
      float4 b1 = *(const float4*)&Bs[p*132 + tx*8 + 4];
      float ar[4]={a4.x,a4.y,a4.z,a4.w};
      float bc[8]={b0.x,b0.y,b0.z,b0.w,b1.x,b1.y,b1.z,b1.w};
      #pragma unroll
      for (int ii=0;ii<4;ii++)
        #pragma unroll
        for (int jj=0;jj<8;jj++) acc[ii][jj] += ar[ii]*bc[jj];
    }
  }
  #pragma unroll
  for (int ii=0;ii<4;ii++){
    size_t row = (size_t)(bi*64 + ty*4 + ii)*NW + ct*128 + tx*8;
    *(float4*)&Wz[row]   = make_float4(acc[ii][0],acc[ii][1],acc[ii][2],acc[ii][3]);
    *(float4*)&Wz[row+4] = make_float4(acc[ii][4],acc[ii][5],acc[ii][6],acc[ii][7]);
  }
}

// ---------------- cooperative mega-kernel: chol chain + doubling ONLY ----------------
__global__ __launch_bounds__(256) void k_mega(float* M, float* Linv, float* Gbuf, float* Lbuf,
                                              float* tb)
{
  cg::grid_group gg = cg::this_grid();
  __shared__ float lds[12480];            // 49,920 B -> 3 blocks/CU ceiling
  float* pa = lds;
  float* pb = lds + 4160;
  float* li = lds + 8320;
  int tid = threadIdx.x;

  if (blockIdx.x < 4)
    potf2_body(M, Linv, Gbuf, 0, blockIdx.x, tid, pa, pb, li);
  gg.sync();

  for (int k=0;k<15;k++){
    int nb = 15-k;
    int tpz = nb*(nb+1)/2;
    int ntile = tpz*4;
    for (int t = blockIdx.x; t < ntile; t += gridDim.x){
      int z = t / tpz;
      int tt = t % tpz;
      csf_tile_body(M, Linv, Gbuf, Lbuf, k, z, tt, tid, pa, pb, li);
    }
    gg.sync();
  }

  if (blockIdx.x < 32){
    int pair = blockIdx.x & 7, z = blockIdx.x >> 3;
    dbl1_body(Lbuf, Linv, M, pair, z, tid, pa, pb, li);
  }
  gg.sync();

  for (int g64=2; g64<=8; g64*=2){
    int np = 8/g64, tpp = g64*g64;
    int per_z = np*tpp;
    int ntile = per_z*4;
    for (int t = blockIdx.x; t < ntile; t += gridDim.x){
      int z = t / per_z, rr = t % per_z;
      dblT_body(Lbuf, M, tb, g64, rr, z, tid, pa, pb);
    }
    gg.sync();
    for (int t = blockIdx.x; t < ntile; t += gridDim.x){
      int z = t / per_z, rr = t % per_z;
      dblC_body(tb, M, g64, rr, z, tid, pa, pb);
    }
    if (g64 < 8) gg.sync();
  }
}

// ---------------- fallback wrappers (separate-launch chain) ----------------
__global__ __launch_bounds__(256) void kw_potf2(float* M, float* Linv, float* Gbuf, int k)
{
  __shared__ float lds[12480];
  potf2_body(M, Linv, Gbuf, k, blockIdx.x, threadIdx.x, lds, lds+4160, lds+8320);
}
__global__ __launch_bounds__(256) void kw_csf(float* M, float* Linv, float* Gbuf, float* Lbuf, int k)
{
  __shared__ float lds[12480];
  csf_tile_body(M, Linv, Gbuf, Lbuf, k, blockIdx.z, blockIdx.x, threadIdx.x,
                lds, lds+4160, lds+8320);
}
__global__ __launch_bounds__(256) void kw_dbl1(const float* Lbuf, const float* Linv, float* Tinv)
{
  __shared__ float lds[12480];
  dbl1_body(Lbuf, Linv, Tinv, blockIdx.x, blockIdx.y, threadIdx.x, lds, lds+4160, lds+8320);
}
__global__ __launch_bounds__(256) void kw_dblT(const float* Lbuf, const float* Tinv, float* tb, int g64)
{
  __shared__ float lds[8320];
  dblT_body(Lbuf, Tinv, tb, g64, blockIdx.x, blockIdx.y, threadIdx.x, lds, lds+4160);
}
__global__ __launch_bounds__(256) void kw_dblC(const float* tb, float* Tinv, int g64)
{
  __shared__ float lds[8320];
  dblC_body(tb, Tinv, g64, blockIdx.x, blockIdx.y, threadIdx.x, lds, lds+4160);
}
__global__ __launch_bounds__(256) void kw_wgemm(const float* Tinv, const float* R,
                                                const float* u, float* W)
{
  __shared__ float lds[12800];
  wgemm_body(Tinv, R, u, W, blockIdx.x, blockIdx.y, blockIdx.z, threadIdx.x, lds);
}

// ---------------- Q partials = W^T W (K-split 3), triangle tiles + mirror ----------------
__global__ __launch_bounds__(256) void k_WtW(const float* __restrict__ W,
                                             float* __restrict__ Qa, float* __restrict__ Qb,
                                             float* __restrict__ Qc)
{
  int z = blockIdx.z;
  int ks = blockIdx.x / 36;
  int tt = blockIdx.x % 36, mi = 0;
  while (tt >= mi+1){ tt -= (mi+1); mi++; }
  int mj = tt;
  const float* Wz = W + (size_t)z*NN*NW;
  float* Qz = (ks==0 ? Qa : (ks==1 ? Qb : Qc)) + (size_t)z*NM;
  int mi0 = mi*128, mj0 = mj*128;
  __shared__ float as[16*WSTRIDE];
  __shared__ float bs[16*WSTRIDE];
  int tid = threadIdx.x;
  int ty = tid>>4, tx = tid&15;
  float areg[8], breg[8];
  float acc[8][8] = {};
  int nbase = ks*352;
  int nsteps = (ks==2)?20:22;   // 352+352+320 = 1024
  #pragma unroll
  for (int i=0;i<8;i++){
    int idx=i*256+tid, r=idx>>7, c=idx&127;
    areg[i] = Wz[(size_t)(nbase+r)*NW + mi0 + c];
    breg[i] = Wz[(size_t)(nbase+r)*NW + mj0 + c];
  }
  int ca = CPAD(ty*8), cb = CPAD(tx*8);
  for (int s=0;s<nsteps;s++){
    __syncthreads();
    #pragma unroll
    for (int i=0;i<8;i++){
      int idx=i*256+tid, r=idx>>7, c=idx&127;
      as[r*WSTRIDE+CPAD(c)]=areg[i];
      bs[r*WSTRIDE+CPAD(c)]=breg[i];
    }
    if (s<nsteps-1){
      int n0 = nbase + (s+1)*16;
      #pragma unroll
      for (int i=0;i<8;i++){
        int idx=i*256+tid, r=idx>>7, c=idx&127;
        areg[i] = Wz[(size_t)(n0+r)*NW + mi0 + c];
        breg[i] = Wz[(size_t)(n0+r)*NW + mj0 + c];
      }
    }
    __syncthreads();
    #pragma unroll
    for (int p=0;p<16;p++){
      float4 a0 = *(const float4*)&as[p*WSTRIDE + ca];
      float4 a1 = *(const float4*)&as[p*WSTRIDE + ca + 4];
      float4 b0 = *(const float4*)&bs[p*WSTRIDE + cb];
      float4 b1 = *(const float4*)&bs[p*WSTRIDE + cb + 4];
      float arf[8]={a0.x,a0.y,a0.z,a0.w,a1.x,a1.y,a1.z,a1.w};
      float bcf[8]={b0.x,b0.y,b0.z,b0.w,b1.x,b1.y,b1.z,b1.w};
      #pragma unroll
      for (int ii=0;ii<8;ii++)
        #pragma unroll
        for (int jj=0;jj<8;jj++) acc[ii][jj]+=arf[ii]*bcf[jj];
    }
  }
  for (int ii=0;ii<8;ii++){
    size_t row = (size_t)(mi0 + ty*8 + ii)*NN + mj0 + tx*8;
    *(float4*)&Qz[row]   = make_float4(acc[ii][0],acc[ii][1],acc[ii][2],acc[ii][3]);
    *(float4*)&Qz[row+4] = make_float4(acc[ii][4],acc[ii][5],acc[ii][6],acc[ii][7]);
  }
  if (mi != mj){
    for (int jj=0;jj<8;jj++){
      size_t row = (size_t)(mj0 + tx*8 + jj)*NN + mi0 + ty*8;
      *(float4*)&Qz[row]   = make_float4(acc[0][jj],acc[1][jj],acc[2][jj],acc[3][jj]);
      *(float4*)&Qz[row+4] = make_float4(acc[4][jj],acc[5][jj],acc[6][jj],acc[7][jj]);
    }
  }
}

// ---------------- column-dot partials ----------------
__global__ void k_colmul(const float* __restrict__ W, float* __restrict__ wpart)
{
  int mc = blockIdx.x, z = blockIdx.y, ns = blockIdx.z, tid = threadIdx.x;
  __shared__ float ufs[256];
  const float* Wz = W + (size_t)z*NN*NW;
  ufs[tid] = Wz[(size_t)(ns*256+tid)*NW + 1024 + z];
  __syncthreads();
  int m = mc*256 + tid;
  float acc = 0.f;
  for (int n=0;n<256;n++)
    acc += Wz[(size_t)(ns*256+n)*NW + m]*ufs[n];
  wpart[(size_t)(z*4+ns)*1024 + m] = acc;
}

// ---------------- fmean outputs (outputs 0 and 3) ----------------
__global__ void k_fmeanout(const float* __restrict__ wpart, const GPParams* __restrict__ P,
                           float* __restrict__ out)
{
  int m = blockIdx.x*256 + threadIdx.x;
  float w[4];
  #pragma unroll
  for (int i=0;i<4;i++){
    float s=0.f;
    #pragma unroll
    for (int ns=0;ns<4;ns++) s += wpart[(size_t)(i*4+ns)*1024 + m];
    w[i]=s;
  }
  #pragma unroll
  for (int a=0;a<4;a++){
    float fm = 0.f;
    #pragma unroll
    for (int i=0;i<4;i++) fm += P->G[a*4+i]*w[i];
    out[a*NN + m] = fm;
    out[OFF_M4 + (size_t)m*4 + a] = fm;
  }
}

// ---------------- fvar assembly (output 1) ----------------
__global__ void k_fvar(const float* __restrict__ S, const float* __restrict__ Qa,
                       const float* __restrict__ Qb, const float* __restrict__ Qc,
                       const GPParams* __restrict__ P, float* __restrict__ out)
{
  size_t idx = (size_t)blockIdx.x*256 + threadIdx.x;
  int m = (int)(idx>>10), mp = (int)(idx & 1023);
  float s = S[idx];
  float q[4];
  #pragma unroll
  for (int i=0;i<4;i++)
    q[i] = Qa[(size_t)i*NM + idx] + Qb[(size_t)i*NM + idx] + Qc[(size_t)i*NM + idx];
  float* fv = out + OFF_FVAR;
  #pragma unroll
  for (int a=0;a<4;a++)
    #pragma unroll
    for (int b=0;b<4;b++){
      float val = P->tk[a*4+b]*s;
      #pragma unroll
      for (int i=0;i<4;i++) val -= P->G[a*4+i]*P->G[b*4+i]*q[i];
      fv[(size_t)(a*NN+m)*BIG + (size_t)b*NN + mp] = val;
    }
}

// ---------------- noise output (output 2) — runs last ----------------
__global__ void k_noise(const float* __restrict__ logn, float* __restrict__ out)
{
  size_t idx = (size_t)blockIdx.x*256 + threadIdx.x;
  int row = (int)(idx>>12), col = (int)(idx & 4095);
  out[OFF_NOISE + idx] = (row==col) ? expf(logn[row>>10]) : 0.f;
}

extern "C" void kernel_launch(void* const* d_in, const int* in_sizes, int n_in,
                              void* d_out, int out_size, void* d_ws, size_t ws_size,
                              hipStream_t stream)
{
  const float* X    = (const float*)d_in[0];
  const float* tX   = (const float*)d_in[1];
  const float* Y    = (const float*)d_in[2];
  const float* logn = (const float*)d_in[3];
  const float* cf   = (const float*)d_in[4];
  const float* logv = (const float*)d_in[5];
  const float* logls= (const float*)d_in[6];
  float* out = (float*)d_out;

  size_t need_floats = 64 + 4096 + 16384
                     + 2*(size_t)NM + 4*(size_t)NM + 262144 + 262144
                     + 4*(size_t)NM + 4*(size_t)NM;
  float* base;
  if (ws_size >= (need_floats + 1024)*sizeof(float)) base = (float*)d_ws;
  else base = out + OFF_NOISE;  // noise region as scratch; k_noise runs last

  GPParams* P  = (GPParams*)base;
  float* u     = base + 64;
  float* wpart = u + 4096;
  float* R     = wpart + 16384;
  float* S     = R + NM;
  float* M     = S + NM;
  float* Linv  = M + 4*(size_t)NM;
  float* Gbuf  = Linv + 262144;
  float* TQ    = Gbuf + 262144;
  float* Lbuf  = TQ + 4*(size_t)NM;
  float* W     = out + OFF_FVAR;
  float* Qa    = M;
  float* Qb    = Lbuf;
  float* Qc    = TQ;
  float* tb    = TQ;

  dim3 b16(16,16);

  k_prep<<<1, 1, 0, stream>>>(logn, cf, logv, P);
  k_rbf <<<dim3(64,64), b16, 0, stream>>>(X,  tX, logls, R);
  k_rbf <<<dim3(64,64), b16, 0, stream>>>(tX, tX, logls, S);
  k_rbfM<<<dim3(64,64), b16, 0, stream>>>(X, logls, P, M);
  k_uvec<<<dim3(4), 256, 0, stream>>>(Y, P, u);

  // Cooperative chol+doubling chain — only if >= 2 blocks/CU co-resident; else launch chain.
  int maxb = 0;
  hipError_t oe = hipOccupancyMaxActiveBlocksPerMultiprocessor(&maxb, k_mega, 256, 0);
  bool coop_done = false;
  if (oe == hipSuccess && maxb >= 2){
    int bpc = (maxb < 3) ? maxb : 3;
    void* kargs[] = { (void*)&M, (void*)&Linv, (void*)&Gbuf, (void*)&Lbuf, (void*)&tb };
    hipError_t ce = hipLaunchCooperativeKernel((const void*)k_mega, dim3(bpc*256), dim3(256),
                                               kargs, 0, stream);
    if (ce == hipSuccess) coop_done = true;
    else (void)hipGetLastError();
  }
  if (!coop_done){
    kw_potf2<<<dim3(4), 256, 0, stream>>>(M, Linv, Gbuf, 0);
    for (int k=0;k<15;k++){
      int nb = 15-k;
      kw_csf<<<dim3(nb*(nb+1)/2, 1, 4), 256, 0, stream>>>(M, Linv, Gbuf, Lbuf, k);
    }
    kw_dbl1<<<dim3(8,4), 256, 0, stream>>>(Lbuf, Linv, M);
    for (int g64=2; g64<=8; g64*=2){
      int np = 8/g64;
      kw_dblT<<<dim3(np*g64*g64, 4), 256, 0, stream>>>(Lbuf, M, tb, g64);
      kw_dblC<<<dim3(np*g64*g64, 4), 256, 0, stream>>>(tb, M, g64);
    }
  }

  // W = Tinv * [R | u]  (big grid, no need for coop)
  kw_wgemm<<<dim3(9,16,4), 256, 0, stream>>>(M, R, u, W);

  // Q = W^T W (three K-chunk partials)
  k_WtW<<<dim3(108,1,4), 256, 0, stream>>>(W, Qa, Qb, Qc);

  k_colmul<<<dim3(4,4,4), 256, 0, stream>>>(W, wpart);
  k_fmeanout<<<dim3(4), 256, 0, stream>>>(wpart, P, out);
  k_fvar<<<dim3(NM/256), 256, 0, stream>>>(S, Qa, Qb, Qc, P, out);
  k_noise<<<dim3(16777216/256), 256, 0, stream>>>(logn, out); // last: may overwrite scratch
}